// Round 1
// baseline (1968.472 us; speedup 1.0000x reference)
//
#include <hip/hip_runtime.h>

#define GN_EPS 1e-5f

__device__ __forceinline__ float sigmoidf_(float x){ return 1.0f/(1.0f+__expf(-x)); }
__device__ __forceinline__ float bcast_(float v, int k){
  return __int_as_float(__builtin_amdgcn_readlane(__float_as_int(v), k));
}

// ---------------- dis = deg^-0.5 (deg includes self-loop) ----------------
__global__ void fill1_kernel(float* d, int n){
  int i = blockIdx.x*blockDim.x+threadIdx.x;
  if (i < n) d[i] = 1.0f;
}
__global__ void deg_kernel(const int* __restrict__ ei, float* d, int E){
  int e = blockIdx.x*blockDim.x+threadIdx.x;
  if (e < E) atomicAdd(&d[ei[E+e]], 1.0f);
}
__global__ void dis_kernel(float* d, int n){
  int i = blockIdx.x*blockDim.x+threadIdx.x;
  if (i < n) d[i] = rsqrtf(d[i]);  // deg >= 1 always (self loop)
}

// ---------------- generic single-input matvec: y = x @ W + b ----------------
template<int K_IN, int C_OUT>
__global__ __launch_bounds__(256) void mm1_kernel(
    const float* __restrict__ x, const float* __restrict__ W,
    const float* __restrict__ b, float* __restrict__ y, int n){
  __shared__ float sW[K_IN*C_OUT];
  for (int i = threadIdx.x; i < K_IN*C_OUT; i += 256) sW[i] = W[i];
  __syncthreads();
  const int lane = threadIdx.x & 63;
  const int col  = (lane < C_OUT) ? lane : 0;
  const float bias = b[col];
  int wid = (blockIdx.x*256 + threadIdx.x) >> 6;
  int nw  = (gridDim.x*256) >> 6;
  for (int i = wid; i < n; i += nw){
    float xv = (lane < K_IN) ? x[i*K_IN + lane] : 0.0f;
    float a0 = bias, a1 = 0.0f;
    #pragma unroll
    for (int k = 0; k < K_IN; k += 2){
      a0 += bcast_(xv, k  ) * sW[(k  )*C_OUT + col];
      a1 += bcast_(xv, k+1) * sW[(k+1)*C_OUT + col];
    }
    if (lane < C_OUT) y[i*C_OUT + lane] = a0 + a1;
  }
}

// ---------------- P/Q precompute: P = h@gw1[0:64]+b1, Q = h@gw1[64:128] ----------------
__global__ __launch_bounds__(256) void pq_kernel(
    const float* __restrict__ h, const float* __restrict__ w1,
    const float* __restrict__ b1, float* __restrict__ P, float* __restrict__ Q, int n){
  __shared__ float sW[128*64];
  for (int i = threadIdx.x; i < 128*64; i += 256) sW[i] = w1[i];
  __syncthreads();
  const int lane = threadIdx.x & 63;
  const float bias = b1[lane];
  int wid = (blockIdx.x*256 + threadIdx.x) >> 6;
  int nw  = (gridDim.x*256) >> 6;
  for (int i = wid; i < n; i += nw){
    float hv = h[i*64 + lane];
    float ap0 = bias, ap1 = 0.f, aq0 = 0.f, aq1 = 0.f;
    #pragma unroll
    for (int k = 0; k < 64; k += 2){
      float h0 = bcast_(hv, k), h1 = bcast_(hv, k+1);
      ap0 += h0 * sW[(k   )*64 + lane];
      aq0 += h0 * sW[(64+k)*64 + lane];
      ap1 += h1 * sW[(k+1   )*64 + lane];
      aq1 += h1 * sW[(64+k+1)*64 + lane];
    }
    P[i*64+lane] = ap0 + ap1;
    Q[i*64+lane] = aq0 + aq1;
  }
}

// ---------------- dual-input matvec (K=128): acc = [in1,in2*dis] @ W + b ----------------
// MODE 0: out = sigmoid(acc)                              (z)
// MODE 1: out = sigmoid(acc) * in1                        (rh = r*h, in1=h)
// MODE 2: hc = relu(acc); out = (1-z)*h + z*hc            (in1=rh, in2=aggr; zb, hb extra)
// MODE 3: out = acc (no dis scaling)                      (fc1: in1=h0, in2=h)
template<int MODE>
__global__ __launch_bounds__(256) void mm2_kernel(
    const float* __restrict__ in1, const float* __restrict__ in2,
    const float* __restrict__ dis,
    const float* __restrict__ W, const float* __restrict__ b,
    const float* __restrict__ zb, const float* __restrict__ hb,
    float* __restrict__ out, int n){
  __shared__ float sW[128*64];
  for (int i = threadIdx.x; i < 128*64; i += 256) sW[i] = W[i];
  __syncthreads();
  const int lane = threadIdx.x & 63;
  const float bias = b[lane];
  int wid = (blockIdx.x*256 + threadIdx.x) >> 6;
  int nw  = (gridDim.x*256) >> 6;
  for (int i = wid; i < n; i += nw){
    float v1 = in1[i*64 + lane];
    float v2 = in2[i*64 + lane];
    if (MODE != 3) v2 *= dis[i];
    float a0 = bias, a1 = 0.f;
    #pragma unroll
    for (int k = 0; k < 64; ++k){
      a0 += bcast_(v1, k) * sW[(k   )*64 + lane];
      a1 += bcast_(v2, k) * sW[(64+k)*64 + lane];
    }
    float acc = a0 + a1;
    float o;
    if (MODE == 0) o = sigmoidf_(acc);
    else if (MODE == 1) o = sigmoidf_(acc) * v1;
    else if (MODE == 2){
      float hc = fmaxf(acc, 0.f);
      float z  = zb[i*64 + lane];
      float hv = hb[i*64 + lane];
      o = (1.0f - z)*hv + z*hc;
    } else o = acc;
    out[i*64 + lane] = o;
  }
}

// ---------------- edge kernel ----------------
__global__ __launch_bounds__(256) void edge_kernel(
    const int* __restrict__ ei, const float* __restrict__ ea,
    const float* __restrict__ P, const float* __restrict__ Q,
    const float* __restrict__ h, const float* __restrict__ dis,
    const float* __restrict__ w2, const float* __restrict__ b2,
    const float* __restrict__ w1e, const float* __restrict__ w3,
    const float* __restrict__ b3,
    float* __restrict__ aggr, int E, int n){
  const int lane = threadIdx.x & 63;
  float w2c[64];
  #pragma unroll
  for (int k = 0; k < 64; ++k) w2c[k] = w2[k*64 + lane];
  const float b2v = b2[lane], w1ev = w1e[lane], w3v = w3[lane], b3v = b3[0];
  int wid = (blockIdx.x*256 + threadIdx.x) >> 6;
  int nw  = (gridDim.x*256) >> 6;
  const int tot = E + n;
  for (int e = wid; e < tot; e += nw){
    int r, c; float eav;
    if (e < E){ r = ei[e]; c = ei[E+e]; eav = ea[e]; }
    else      { r = e - E; c = r;       eav = 1.0f;  }
    float g1 = fmaxf(P[c*64 + lane] + Q[r*64 + lane] + eav*w1ev, 0.0f);
    float a0 = b2v, a1 = 0.f;
    #pragma unroll
    for (int k = 0; k < 64; k += 2){
      a0 += bcast_(g1, k  ) * w2c[k  ];
      a1 += bcast_(g1, k+1) * w2c[k+1];
    }
    float g2 = fmaxf(a0 + a1, 0.0f);
    float p = g2 * w3v;
    #pragma unroll
    for (int off = 32; off > 0; off >>= 1) p += __shfl_xor(p, off);
    float gate = sigmoidf_(p + b3v);
    float msg = gate * dis[r] * h[r*64 + lane];
    atomicAdd(&aggr[c*64 + lane], msg);
  }
}

// ---------------- graph norm ----------------
template<int C>
__global__ __launch_bounds__(256) void norm_stats_kernel(
    const float* __restrict__ x, int n, float* __restrict__ stats){
  __shared__ float ssum[256], ssq[256];
  const int tid = threadIdx.x;
  const int c = tid % C;
  int row = (blockIdx.x*256 + tid) / C;
  int stride = (gridDim.x*256) / C;
  float s = 0.f, q = 0.f;
  for (int i = row; i < n; i += stride){
    float v = x[i*C + c];
    s += v; q += v*v;
  }
  ssum[tid] = s; ssq[tid] = q;
  __syncthreads();
  if (tid < C){
    float S = 0.f, Q2 = 0.f;
    for (int t = tid; t < 256; t += C){ S += ssum[t]; Q2 += ssq[t]; }
    atomicAdd(&stats[tid], S);
    atomicAdd(&stats[C + tid], Q2);
  }
}

template<int C, int RELU, int DUAL>
__global__ __launch_bounds__(256) void norm_apply_kernel(
    const float* __restrict__ x, const float* __restrict__ stats,
    const float* __restrict__ w, const float* __restrict__ b,
    const float* __restrict__ ms, float* __restrict__ y,
    float* __restrict__ y2, int n){
  const float invN = 1.0f / (float)n;
  int idx = blockIdx.x*256 + threadIdx.x;
  int step = gridDim.x*256;
  for (; idx < n*C; idx += step){
    int c = idx % C;
    float mean = stats[c] * invN;
    float mm = mean * ms[c];
    float var = stats[C + c]*invN - mm*(2.0f*mean - mm);
    float inv = rsqrtf(fmaxf(var, 0.0f) + GN_EPS);
    float v = (x[idx] - mm)*inv*w[c] + b[c];
    if (RELU) v = fmaxf(v, 0.0f);
    y[idx] = v;
    if (DUAL) y2[idx] = v;
  }
}

// ---------------- fc2 ----------------
__global__ __launch_bounds__(256) void fc2_kernel(
    const float* __restrict__ x, const float* __restrict__ w,
    const float* __restrict__ b, float* __restrict__ out, int n){
  int i = blockIdx.x*blockDim.x + threadIdx.x;
  if (i >= n) return;
  float a0 = b[0], a1 = b[1];
  const float4* xr = (const float4*)(x + i*64);
  #pragma unroll
  for (int k4 = 0; k4 < 16; ++k4){
    float4 v = xr[k4];
    int k = k4*4;
    a0 += v.x*w[(k+0)*2+0] + v.y*w[(k+1)*2+0] + v.z*w[(k+2)*2+0] + v.w*w[(k+3)*2+0];
    a1 += v.x*w[(k+0)*2+1] + v.y*w[(k+1)*2+1] + v.z*w[(k+2)*2+1] + v.w*w[(k+3)*2+1];
  }
  out[i*2+0] = a0;
  out[i*2+1] = a1;
}

extern "C" void kernel_launch(void* const* d_in, const int* in_sizes, int n_in,
                              void* d_out, int out_size, void* d_ws, size_t ws_size,
                              hipStream_t stream){
  const float* x          = (const float*)d_in[0];
  const int*   ei         = (const int*)  d_in[1];
  const float* ea         = (const float*)d_in[2];
  // d_in[3] = batch (all zeros) unused
  const float* preproc_w  = (const float*)d_in[4];
  const float* preproc_b  = (const float*)d_in[5];
  const float* gn_pre_w   = (const float*)d_in[6];
  const float* gn_pre_b   = (const float*)d_in[7];
  const float* gn_pre_ms  = (const float*)d_in[8];
  const float* init_w     = (const float*)d_in[9];
  const float* init_b     = (const float*)d_in[10];
  const float* gn_init_w  = (const float*)d_in[11];
  const float* gn_init_b  = (const float*)d_in[12];
  const float* gn_init_ms = (const float*)d_in[13];
  const float* gate_w1    = (const float*)d_in[14];
  const float* gate_b1    = (const float*)d_in[15];
  const float* gate_w2    = (const float*)d_in[16];
  const float* gate_b2    = (const float*)d_in[17];
  const float* gate_w3    = (const float*)d_in[18];
  const float* gate_b3    = (const float*)d_in[19];
  const float* lin_z_w    = (const float*)d_in[20];
  const float* lin_z_b    = (const float*)d_in[21];
  const float* lin_r_w    = (const float*)d_in[22];
  const float* lin_r_b    = (const float*)d_in[23];
  const float* lin_h_w    = (const float*)d_in[24];
  const float* lin_h_b    = (const float*)d_in[25];
  const float* gn_ggnn_w  = (const float*)d_in[26];
  const float* gn_ggnn_b  = (const float*)d_in[27];
  const float* gn_ggnn_ms = (const float*)d_in[28];
  const float* fc1_w      = (const float*)d_in[29];
  const float* fc1_b      = (const float*)d_in[30];
  const float* gn_fc1_w   = (const float*)d_in[31];
  const float* gn_fc1_b   = (const float*)d_in[32];
  const float* gn_fc1_ms  = (const float*)d_in[33];
  const float* fc2_w      = (const float*)d_in[34];
  const float* fc2_b      = (const float*)d_in[35];

  const int N = in_sizes[3];      // batch has N entries
  const int E = in_sizes[1] / 2;  // edge_index is (2,E)

  // workspace layout (floats)
  float* ws   = (float*)d_ws;
  float* h    = ws;                // N*64
  float* h0   = h    + (size_t)64*N;
  float* P    = h0   + (size_t)64*N;
  float* Q    = P    + (size_t)64*N;
  float* aggr = Q    + (size_t)64*N;
  float* dis  = aggr + (size_t)64*N;  // N
  float* stats= dis  + N;             // 128
  size_t need = ((size_t)64*N*5 + N + 128) * sizeof(float);
  if (ws_size < need) return;  // insufficient workspace -> fail loudly via validation

  const int GB = 1024;   // node-kernel blocks
  const int EB = 2048;   // edge-kernel blocks

  // ---- dis ----
  fill1_kernel<<<(N+255)/256, 256, 0, stream>>>(dis, N);
  deg_kernel  <<<(E+255)/256, 256, 0, stream>>>(ei, dis, E);
  dis_kernel  <<<(N+255)/256, 256, 0, stream>>>(dis, N);

  // ---- preproc: x[N,16] @ [16,32] -> P(32) ; norm+relu -> Q(32) ----
  mm1_kernel<16,32><<<GB, 256, 0, stream>>>(x, preproc_w, preproc_b, P, N);
  hipMemsetAsync(stats, 0, 2*64*sizeof(float), stream);
  norm_stats_kernel<32><<<256, 256, 0, stream>>>(P, N, stats);
  norm_apply_kernel<32,1,0><<<2048, 256, 0, stream>>>(P, stats, gn_pre_w, gn_pre_b, gn_pre_ms, Q, nullptr, N);

  // ---- init: Q(32) @ [32,64] -> P(64) ; norm+relu -> h0 and h ----
  mm1_kernel<32,64><<<GB, 256, 0, stream>>>(Q, init_w, init_b, P, N);
  hipMemsetAsync(stats, 0, 2*64*sizeof(float), stream);
  norm_stats_kernel<64><<<256, 256, 0, stream>>>(P, N, stats);
  norm_apply_kernel<64,1,1><<<2048, 256, 0, stream>>>(P, stats, gn_init_w, gn_init_b, gn_init_ms, h0, h, N);

  // ---- 4 tied GGNN layers ----
  for (int layer = 0; layer < 4; ++layer){
    pq_kernel<<<GB, 256, 0, stream>>>(h, gate_w1, gate_b1, P, Q, N);
    hipMemsetAsync(aggr, 0, (size_t)64*N*sizeof(float), stream);
    edge_kernel<<<EB, 256, 0, stream>>>(ei, ea, P, Q, h, dis,
                                        gate_w2, gate_b2, gate_w1 + 128*64,
                                        gate_w3, gate_b3, aggr, E, N);
    // z -> P ; rh -> Q ; hnew -> P (in place over z)
    mm2_kernel<0><<<GB, 256, 0, stream>>>(h, aggr, dis, lin_z_w, lin_z_b, nullptr, nullptr, P, N);
    mm2_kernel<1><<<GB, 256, 0, stream>>>(h, aggr, dis, lin_r_w, lin_r_b, nullptr, nullptr, Q, N);
    mm2_kernel<2><<<GB, 256, 0, stream>>>(Q, aggr, dis, lin_h_w, lin_h_b, P, h, P, N);
    hipMemsetAsync(stats, 0, 2*64*sizeof(float), stream);
    norm_stats_kernel<64><<<256, 256, 0, stream>>>(P, N, stats);
    norm_apply_kernel<64,0,0><<<2048, 256, 0, stream>>>(P, stats, gn_ggnn_w, gn_ggnn_b, gn_ggnn_ms, h, nullptr, N);
  }

  // ---- fc1: [h0,h] @ [128,64] -> P ; norm+relu -> Q ----
  mm2_kernel<3><<<GB, 256, 0, stream>>>(h0, h, nullptr, fc1_w, fc1_b, nullptr, nullptr, P, N);
  hipMemsetAsync(stats, 0, 2*64*sizeof(float), stream);
  norm_stats_kernel<64><<<256, 256, 0, stream>>>(P, N, stats);
  norm_apply_kernel<64,1,0><<<2048, 256, 0, stream>>>(P, stats, gn_fc1_w, gn_fc1_b, gn_fc1_ms, Q, nullptr, N);

  // ---- fc2 -> out [N,2] ----
  fc2_kernel<<<(N+255)/256, 256, 0, stream>>>(Q, fc2_w, fc2_b, (float*)d_out, N);
}

// Round 2
// 1486.251 us; speedup vs baseline: 1.3245x; 1.3245x over previous
//
#include <hip/hip_runtime.h>

#define GN_EPS 1e-5f

typedef _Float16 half8 __attribute__((ext_vector_type(8)));
typedef float floatx4 __attribute__((ext_vector_type(4)));

__device__ __forceinline__ float sigmoidf_(float x){ return 1.0f/(1.0f+__expf(-x)); }
__device__ __forceinline__ float bcast_(float v, int k){
  return __int_as_float(__builtin_amdgcn_readlane(__float_as_int(v), k));
}

// ---------------- dis = deg^-0.5 (deg includes self-loop) ----------------
__global__ void fill1_kernel(float* d, int n){
  int i = blockIdx.x*blockDim.x+threadIdx.x;
  if (i < n) d[i] = 1.0f;
}
__global__ void deg_kernel(const int* __restrict__ ei, float* d, int E){
  int e = blockIdx.x*blockDim.x+threadIdx.x;
  if (e < E) atomicAdd(&d[ei[E+e]], 1.0f);
}
__global__ void dis_kernel(float* d, int n){
  int i = blockIdx.x*blockDim.x+threadIdx.x;
  if (i < n) d[i] = rsqrtf(d[i]);  // deg >= 1 always (self loop)
}

// ---------------- generic single-input matvec: y = x @ W + b ----------------
template<int K_IN, int C_OUT>
__global__ __launch_bounds__(256) void mm1_kernel(
    const float* __restrict__ x, const float* __restrict__ W,
    const float* __restrict__ b, float* __restrict__ y, int n){
  __shared__ float sW[K_IN*C_OUT];
  for (int i = threadIdx.x; i < K_IN*C_OUT; i += 256) sW[i] = W[i];
  __syncthreads();
  const int lane = threadIdx.x & 63;
  const int col  = (lane < C_OUT) ? lane : 0;
  const float bias = b[col];
  int wid = (blockIdx.x*256 + threadIdx.x) >> 6;
  int nw  = (gridDim.x*256) >> 6;
  for (int i = wid; i < n; i += nw){
    float xv = (lane < K_IN) ? x[i*K_IN + lane] : 0.0f;
    float a0 = bias, a1 = 0.0f;
    #pragma unroll
    for (int k = 0; k < K_IN; k += 2){
      a0 += bcast_(xv, k  ) * sW[(k  )*C_OUT + col];
      a1 += bcast_(xv, k+1) * sW[(k+1)*C_OUT + col];
    }
    if (lane < C_OUT) y[i*C_OUT + lane] = a0 + a1;
  }
}

// ---------------- P/Q precompute: P = h@gw1[0:64]+b1, Q = h@gw1[64:128] ----------------
__global__ __launch_bounds__(256) void pq_kernel(
    const float* __restrict__ h, const float* __restrict__ w1,
    const float* __restrict__ b1, float* __restrict__ P, float* __restrict__ Q, int n){
  __shared__ float sW[128*64];
  for (int i = threadIdx.x; i < 128*64; i += 256) sW[i] = w1[i];
  __syncthreads();
  const int lane = threadIdx.x & 63;
  const float bias = b1[lane];
  int wid = (blockIdx.x*256 + threadIdx.x) >> 6;
  int nw  = (gridDim.x*256) >> 6;
  for (int i = wid; i < n; i += nw){
    float hv = h[i*64 + lane];
    float ap0 = bias, ap1 = 0.f, aq0 = 0.f, aq1 = 0.f;
    #pragma unroll
    for (int k = 0; k < 64; k += 2){
      float h0 = bcast_(hv, k), h1 = bcast_(hv, k+1);
      ap0 += h0 * sW[(k   )*64 + lane];
      aq0 += h0 * sW[(64+k)*64 + lane];
      ap1 += h1 * sW[(k+1   )*64 + lane];
      aq1 += h1 * sW[(64+k+1)*64 + lane];
    }
    P[i*64+lane] = ap0 + ap1;
    Q[i*64+lane] = aq0 + aq1;
  }
}

// ---------------- dual-input matvec (K=128) ----------------
// MODE 0: out = sigmoid(acc)                              (z)
// MODE 1: out = sigmoid(acc) * in1                        (rh = r*h, in1=h)
// MODE 2: hc = relu(acc); out = (1-z)*h + z*hc            (in1=rh, in2=aggr; zb, hb extra)
// MODE 3: out = acc (no dis scaling)                      (fc1: in1=h0, in2=h)
template<int MODE>
__global__ __launch_bounds__(256) void mm2_kernel(
    const float* __restrict__ in1, const float* __restrict__ in2,
    const float* __restrict__ dis,
    const float* __restrict__ W, const float* __restrict__ b,
    const float* __restrict__ zb, const float* __restrict__ hb,
    float* __restrict__ out, int n){
  __shared__ float sW[128*64];
  for (int i = threadIdx.x; i < 128*64; i += 256) sW[i] = W[i];
  __syncthreads();
  const int lane = threadIdx.x & 63;
  const float bias = b[lane];
  int wid = (blockIdx.x*256 + threadIdx.x) >> 6;
  int nw  = (gridDim.x*256) >> 6;
  for (int i = wid; i < n; i += nw){
    float v1 = in1[i*64 + lane];
    float v2 = in2[i*64 + lane];
    if (MODE != 3) v2 *= dis[i];
    float a0 = bias, a1 = 0.f;
    #pragma unroll
    for (int k = 0; k < 64; ++k){
      a0 += bcast_(v1, k) * sW[(k   )*64 + lane];
      a1 += bcast_(v2, k) * sW[(64+k)*64 + lane];
    }
    float acc = a0 + a1;
    float o;
    if (MODE == 0) o = sigmoidf_(acc);
    else if (MODE == 1) o = sigmoidf_(acc) * v1;
    else if (MODE == 2){
      float hc = fmaxf(acc, 0.f);
      float z  = zb[i*64 + lane];
      float hv = hb[i*64 + lane];
      o = (1.0f - z)*hv + z*hc;
    } else o = acc;
    out[i*64 + lane] = o;
  }
}

// ---------------- edge kernel: MFMA f16 gate MLP, 16 edges per wave-tile ----------------
// g1[e][k] = relu(P[c_e][k] + Q[r_e][k] + ea_e * w1e[k])   (built directly in A-frag layout)
// g2 = relu(g1 @ w2 + b2)  via 8x mfma_f32_16x16x32_f16 (4 c-tiles x 2 k-chunks)
// gate_e = sigmoid(sum_c g2[e][c]*w3[c] + b3); msg = gate*dis[r]*h[r] -> atomicAdd aggr[c]
__global__ __launch_bounds__(256) void edge_mfma_kernel(
    const int* __restrict__ ei, const float* __restrict__ ea,
    const float* __restrict__ P, const float* __restrict__ Q,
    const float* __restrict__ h, const float* __restrict__ dis,
    const float* __restrict__ w2, const float* __restrict__ b2,
    const float* __restrict__ w1e, const float* __restrict__ w3,
    const float* __restrict__ b3,
    float* __restrict__ aggr, int E, int n)
{
  const int lane = threadIdx.x & 63;
  const int g16  = lane >> 4;   // k-chunk group / D-row group
  const int l16  = lane & 15;   // edge-in-tile (A) / column-in-tile (B, D)

  // B fragments: B[k][n-col], col = l16 within c-tile t, k = kh*32 + g16*8 + j
  half8 bfrag[4][2];
  #pragma unroll
  for (int t = 0; t < 4; ++t)
    #pragma unroll
    for (int kh = 0; kh < 2; ++kh)
      #pragma unroll
      for (int j = 0; j < 8; ++j)
        bfrag[t][kh][j] = (_Float16)w2[(kh*32 + g16*8 + j)*64 + t*16 + l16];

  float w1f[16];
  #pragma unroll
  for (int kh = 0; kh < 2; ++kh)
    #pragma unroll
    for (int j = 0; j < 8; ++j)
      w1f[kh*8+j] = w1e[kh*32 + g16*8 + j];

  float w3f[4], b2f[4];
  #pragma unroll
  for (int t = 0; t < 4; ++t){ w3f[t] = w3[t*16 + l16]; b2f[t] = b2[t*16 + l16]; }
  const float b3v = b3[0];

  const int tot   = E + n;
  const int tiles = (tot + 15) >> 4;
  int wid = (blockIdx.x*blockDim.x + threadIdx.x) >> 6;
  int nw  = (gridDim.x*blockDim.x) >> 6;

  for (int tile = wid; tile < tiles; tile += nw){
    // this lane's edge (for A-frag build): edge l16 of the tile
    int e  = tile*16 + l16;
    int ec = min(e, tot-1);
    bool is_e = ec < E;
    int  il = is_e ? ec : 0;
    int rr = ei[il], cc = ei[E+il];
    float eav = is_e ? ea[il] : 1.0f;
    int r = is_e ? rr : ec - E;
    int c = is_e ? cc : ec - E;

    // A fragments: row = l16 (edge), k = kh*32 + g16*8 + j
    half8 afrag[2];
    #pragma unroll
    for (int kh = 0; kh < 2; ++kh){
      const float* pr = P + (size_t)c*64 + kh*32 + g16*8;
      const float* qr = Q + (size_t)r*64 + kh*32 + g16*8;
      float4 p0 = *(const float4*)pr;
      float4 p1 = *(const float4*)(pr+4);
      float4 q0 = *(const float4*)qr;
      float4 q1 = *(const float4*)(qr+4);
      float g[8] = {p0.x+q0.x, p0.y+q0.y, p0.z+q0.z, p0.w+q0.w,
                    p1.x+q1.x, p1.y+q1.y, p1.z+q1.z, p1.w+q1.w};
      #pragma unroll
      for (int j = 0; j < 8; ++j)
        afrag[kh][j] = (_Float16)fmaxf(g[j] + eav*w1f[kh*8+j], 0.0f);
    }

    // 8 MFMAs: D[edge][col], col = t*16+l16, row(edge) = g16*4 + reg
    floatx4 acc[4];
    #pragma unroll
    for (int t = 0; t < 4; ++t){ acc[t][0]=b2f[t]; acc[t][1]=b2f[t]; acc[t][2]=b2f[t]; acc[t][3]=b2f[t]; }
    #pragma unroll
    for (int t = 0; t < 4; ++t){
      acc[t] = __builtin_amdgcn_mfma_f32_16x16x32_f16(afrag[0], bfrag[t][0], acc[t], 0, 0, 0);
      acc[t] = __builtin_amdgcn_mfma_f32_16x16x32_f16(afrag[1], bfrag[t][1], acc[t], 0, 0, 0);
    }

    // gate partials: s[reg] for edge g16*4+reg, summed over this lane's column l16 (4 tiles)
    float s[4] = {0.f,0.f,0.f,0.f};
    #pragma unroll
    for (int t = 0; t < 4; ++t)
      #pragma unroll
      for (int rg = 0; rg < 4; ++rg)
        s[rg] += fmaxf(acc[t][rg], 0.0f) * w3f[t];
    // reduce over the 16 lanes (columns) within group g16
    #pragma unroll
    for (int rg = 0; rg < 4; ++rg){
      #pragma unroll
      for (int off = 1; off < 16; off <<= 1)
        s[rg] += __shfl_xor(s[rg], off);
      s[rg] = sigmoidf_(s[rg] + b3v);
    }
    // gate of edge i lives in lanes [ (i>>2)*16 .. +15 ], slot s[i&3]

    int ebase = tile*16;
    #pragma unroll
    for (int i = 0; i < 16; ++i){
      if (ebase + i >= tot) break;  // uniform
      float gi = bcast_(s[i & 3], (i >> 2) * 16);
      int ri = __builtin_amdgcn_readlane(r, i);
      int ci = __builtin_amdgcn_readlane(c, i);
      float f = gi * dis[ri];
      atomicAdd(&aggr[(size_t)ci*64 + lane], f * h[(size_t)ri*64 + lane]);
    }
  }
}

// ---------------- graph norm ----------------
template<int C>
__global__ __launch_bounds__(256) void norm_stats_kernel(
    const float* __restrict__ x, int n, float* __restrict__ stats){
  __shared__ float ssum[256], ssq[256];
  const int tid = threadIdx.x;
  const int c = tid % C;
  int row = (blockIdx.x*256 + tid) / C;
  int stride = (gridDim.x*256) / C;
  float s = 0.f, q = 0.f;
  for (int i = row; i < n; i += stride){
    float v = x[i*C + c];
    s += v; q += v*v;
  }
  ssum[tid] = s; ssq[tid] = q;
  __syncthreads();
  if (tid < C){
    float S = 0.f, Q2 = 0.f;
    for (int t = tid; t < 256; t += C){ S += ssum[t]; Q2 += ssq[t]; }
    atomicAdd(&stats[tid], S);
    atomicAdd(&stats[C + tid], Q2);
  }
}

template<int C, int RELU, int DUAL>
__global__ __launch_bounds__(256) void norm_apply_kernel(
    const float* __restrict__ x, const float* __restrict__ stats,
    const float* __restrict__ w, const float* __restrict__ b,
    const float* __restrict__ ms, float* __restrict__ y,
    float* __restrict__ y2, int n){
  const float invN = 1.0f / (float)n;
  int idx = blockIdx.x*256 + threadIdx.x;
  int step = gridDim.x*256;
  for (; idx < n*C; idx += step){
    int c = idx % C;
    float mean = stats[c] * invN;
    float mm = mean * ms[c];
    float var = stats[C + c]*invN - mm*(2.0f*mean - mm);
    float inv = rsqrtf(fmaxf(var, 0.0f) + GN_EPS);
    float v = (x[idx] - mm)*inv*w[c] + b[c];
    if (RELU) v = fmaxf(v, 0.0f);
    y[idx] = v;
    if (DUAL) y2[idx] = v;
  }
}

// ---------------- fc2 ----------------
__global__ __launch_bounds__(256) void fc2_kernel(
    const float* __restrict__ x, const float* __restrict__ w,
    const float* __restrict__ b, float* __restrict__ out, int n){
  int i = blockIdx.x*blockDim.x + threadIdx.x;
  if (i >= n) return;
  float a0 = b[0], a1 = b[1];
  const float4* xr = (const float4*)(x + i*64);
  #pragma unroll
  for (int k4 = 0; k4 < 16; ++k4){
    float4 v = xr[k4];
    int k = k4*4;
    a0 += v.x*w[(k+0)*2+0] + v.y*w[(k+1)*2+0] + v.z*w[(k+2)*2+0] + v.w*w[(k+3)*2+0];
    a1 += v.x*w[(k+0)*2+1] + v.y*w[(k+1)*2+1] + v.z*w[(k+2)*2+1] + v.w*w[(k+3)*2+1];
  }
  out[i*2+0] = a0;
  out[i*2+1] = a1;
}

extern "C" void kernel_launch(void* const* d_in, const int* in_sizes, int n_in,
                              void* d_out, int out_size, void* d_ws, size_t ws_size,
                              hipStream_t stream){
  const float* x          = (const float*)d_in[0];
  const int*   ei         = (const int*)  d_in[1];
  const float* ea         = (const float*)d_in[2];
  // d_in[3] = batch (all zeros) unused
  const float* preproc_w  = (const float*)d_in[4];
  const float* preproc_b  = (const float*)d_in[5];
  const float* gn_pre_w   = (const float*)d_in[6];
  const float* gn_pre_b   = (const float*)d_in[7];
  const float* gn_pre_ms  = (const float*)d_in[8];
  const float* init_w     = (const float*)d_in[9];
  const float* init_b     = (const float*)d_in[10];
  const float* gn_init_w  = (const float*)d_in[11];
  const float* gn_init_b  = (const float*)d_in[12];
  const float* gn_init_ms = (const float*)d_in[13];
  const float* gate_w1    = (const float*)d_in[14];
  const float* gate_b1    = (const float*)d_in[15];
  const float* gate_w2    = (const float*)d_in[16];
  const float* gate_b2    = (const float*)d_in[17];
  const float* gate_w3    = (const float*)d_in[18];
  const float* gate_b3    = (const float*)d_in[19];
  const float* lin_z_w    = (const float*)d_in[20];
  const float* lin_z_b    = (const float*)d_in[21];
  const float* lin_r_w    = (const float*)d_in[22];
  const float* lin_r_b    = (const float*)d_in[23];
  const float* lin_h_w    = (const float*)d_in[24];
  const float* lin_h_b    = (const float*)d_in[25];
  const float* gn_ggnn_w  = (const float*)d_in[26];
  const float* gn_ggnn_b  = (const float*)d_in[27];
  const float* gn_ggnn_ms = (const float*)d_in[28];
  const float* fc1_w      = (const float*)d_in[29];
  const float* fc1_b      = (const float*)d_in[30];
  const float* gn_fc1_w   = (const float*)d_in[31];
  const float* gn_fc1_b   = (const float*)d_in[32];
  const float* gn_fc1_ms  = (const float*)d_in[33];
  const float* fc2_w      = (const float*)d_in[34];
  const float* fc2_b      = (const float*)d_in[35];

  const int N = in_sizes[3];      // batch has N entries
  const int E = in_sizes[1] / 2;  // edge_index is (2,E)

  // workspace layout (floats) — identical to round 1
  float* ws   = (float*)d_ws;
  float* h    = ws;                // N*64
  float* h0   = h    + (size_t)64*N;
  float* P    = h0   + (size_t)64*N;
  float* Q    = P    + (size_t)64*N;
  float* aggr = Q    + (size_t)64*N;
  float* dis  = aggr + (size_t)64*N;  // N
  float* stats= dis  + N;             // 128
  size_t need = ((size_t)64*N*5 + N + 128) * sizeof(float);
  if (ws_size < need) return;

  const int GB = 1024;   // node-kernel blocks
  const int EB = 2048;   // edge-kernel blocks

  // ---- dis ----
  fill1_kernel<<<(N+255)/256, 256, 0, stream>>>(dis, N);
  deg_kernel  <<<(E+255)/256, 256, 0, stream>>>(ei, dis, E);
  dis_kernel  <<<(N+255)/256, 256, 0, stream>>>(dis, N);

  // ---- preproc: x[N,16] @ [16,32] -> P(32) ; norm+relu -> Q(32) ----
  mm1_kernel<16,32><<<GB, 256, 0, stream>>>(x, preproc_w, preproc_b, P, N);
  hipMemsetAsync(stats, 0, 2*64*sizeof(float), stream);
  norm_stats_kernel<32><<<256, 256, 0, stream>>>(P, N, stats);
  norm_apply_kernel<32,1,0><<<2048, 256, 0, stream>>>(P, stats, gn_pre_w, gn_pre_b, gn_pre_ms, Q, nullptr, N);

  // ---- init: Q(32) @ [32,64] -> P(64) ; norm+relu -> h0 and h ----
  mm1_kernel<32,64><<<GB, 256, 0, stream>>>(Q, init_w, init_b, P, N);
  hipMemsetAsync(stats, 0, 2*64*sizeof(float), stream);
  norm_stats_kernel<64><<<256, 256, 0, stream>>>(P, N, stats);
  norm_apply_kernel<64,1,1><<<2048, 256, 0, stream>>>(P, stats, gn_init_w, gn_init_b, gn_init_ms, h0, h, N);

  // ---- 4 tied GGNN layers ----
  for (int layer = 0; layer < 4; ++layer){
    pq_kernel<<<GB, 256, 0, stream>>>(h, gate_w1, gate_b1, P, Q, N);
    hipMemsetAsync(aggr, 0, (size_t)64*N*sizeof(float), stream);
    edge_mfma_kernel<<<EB, 256, 0, stream>>>(ei, ea, P, Q, h, dis,
                                             gate_w2, gate_b2, gate_w1 + 128*64,
                                             gate_w3, gate_b3, aggr, E, N);
    // z -> P ; rh -> Q ; hnew -> P (in place over z)
    mm2_kernel<0><<<GB, 256, 0, stream>>>(h, aggr, dis, lin_z_w, lin_z_b, nullptr, nullptr, P, N);
    mm2_kernel<1><<<GB, 256, 0, stream>>>(h, aggr, dis, lin_r_w, lin_r_b, nullptr, nullptr, Q, N);
    mm2_kernel<2><<<GB, 256, 0, stream>>>(Q, aggr, dis, lin_h_w, lin_h_b, P, h, P, N);
    hipMemsetAsync(stats, 0, 2*64*sizeof(float), stream);
    norm_stats_kernel<64><<<256, 256, 0, stream>>>(P, N, stats);
    norm_apply_kernel<64,0,0><<<2048, 256, 0, stream>>>(P, stats, gn_ggnn_w, gn_ggnn_b, gn_ggnn_ms, h, nullptr, N);
  }

  // ---- fc1: [h0,h] @ [128,64] -> P ; norm+relu -> Q ----
  mm2_kernel<3><<<GB, 256, 0, stream>>>(h0, h, nullptr, fc1_w, fc1_b, nullptr, nullptr, P, N);
  hipMemsetAsync(stats, 0, 2*64*sizeof(float), stream);
  norm_stats_kernel<64><<<256, 256, 0, stream>>>(P, N, stats);
  norm_apply_kernel<64,1,0><<<2048, 256, 0, stream>>>(P, stats, gn_fc1_w, gn_fc1_b, gn_fc1_ms, Q, nullptr, N);

  // ---- fc2 -> out [N,2] ----
  fc2_kernel<<<(N+255)/256, 256, 0, stream>>>(Q, fc2_w, fc2_b, (float*)d_out, N);
}